// Round 10
// baseline (212.779 us; speedup 1.0000x reference)
//
#include <hip/hip_runtime.h>
#include <stdint.h>

// AttentionBlock: B=32, C=512, H=W=32 (N=1024), fp32 in/out.
//   cvt: Wq,Wk,Wv -> fp8 e4m3; Wo -> bf16; bqk=[bq;bk] f32
//   transpose x -> Xt [B,N,C] fp8
//   QK = Xt*[Wq;Wk]^T + [bq;bk]  [B*N,1024] fp8 (Q cols 0-511, K 512-1023)
//   V  = Wv*Xt_b^T + bv          [B][C][N] fp8
//   H  = flash_attn fp8, role-split: 4 QK-waves + 8 PV-waves, 1 barrier/tile
//   out = Wo*H_b^T + bo + x      [B][C][N] fp32 (bf16 gemm)

#define CD 512
#define NSP 1024
#define SCALE_EXP2 0.06376339f   // C^-0.5 * log2(e)

using bf16x8 = __attribute__((ext_vector_type(8))) short;
using f32x4  = __attribute__((ext_vector_type(4))) float;
typedef long i64v;               // 8 x fp8 operand for MFMA

__device__ __forceinline__ unsigned short f2bf(float f) {
    union { float f; unsigned int i; } v; v.f = f;
    unsigned int r = v.i + 0x7FFFu + ((v.i >> 16) & 1u);
    return (unsigned short)(r >> 16);
}
__device__ __forceinline__ unsigned char f2f8(float f) {
    unsigned int r;
    asm("v_cvt_pk_fp8_f32 %0, %1, %1" : "=v"(r) : "v"(f));
    return (unsigned char)(r & 0xffu);
}
__device__ __forceinline__ unsigned int f4_to_f8x4(float a, float b, float c, float d) {
    unsigned int r = 0;
    asm("v_cvt_pk_fp8_f32 %0, %2, %3\n\t"
        "v_cvt_pk_fp8_f32 %0, %4, %5 op_sel:[0,0,1]"
        : "=v"(r) : "0"(r), "v"(a), "v"(b), "v"(c), "v"(d));
    return r;
}
__device__ __forceinline__ void gl_lds16(const void* g, void* l) {
    __builtin_amdgcn_global_load_lds(
        (const __attribute__((address_space(1))) void*)g,
        (__attribute__((address_space(3))) void*)l, 16, 0, 0);
}

// Wq,Wk,Wv -> fp8 (w8, contiguous [3*512][512]); Wo -> bf16; bqk concat f32
__global__ __launch_bounds__(256) void cvt_all(
    const float* __restrict__ Wq, const float* __restrict__ Wk,
    const float* __restrict__ Wv, const float* __restrict__ Wo,
    const float* __restrict__ bq, const float* __restrict__ bk,
    unsigned char* __restrict__ w8, unsigned short* __restrict__ wob,
    float* __restrict__ bqk)
{
    int idx = blockIdx.x * 256 + threadIdx.x;     // 0..1048575
    int which = idx >> 18, off = idx & 262143;
    if (which < 3) {
        const float* src = which == 0 ? Wq : which == 1 ? Wk : Wv;
        w8[idx] = f2f8(src[off]);
    } else {
        wob[off] = f2bf(Wo[off]);
    }
    if (idx < 1024) bqk[idx] = (idx < 512) ? bq[idx] : bk[idx - 512];
}

// x [B][C][N] f32 -> xt [B][N][C] fp8
__global__ __launch_bounds__(256) void transpose_x(const float* __restrict__ x,
                                                   unsigned char* __restrict__ xt) {
    __shared__ float t[32][33];
    int b = blockIdx.z;
    int n0 = blockIdx.x * 32, c0 = blockIdx.y * 32;
    const float* xb = x + (size_t)b * CD * NSP;
    unsigned char* xtb = xt + (size_t)b * NSP * CD;
    int tx = threadIdx.x, ty = threadIdx.y;
    #pragma unroll
    for (int i = 0; i < 4; ++i)
        t[ty + i * 8][tx] = xb[(size_t)(c0 + ty + i * 8) * NSP + n0 + tx];
    __syncthreads();
    #pragma unroll
    for (int i = 0; i < 4; ++i)
        xtb[(size_t)(n0 + ty + i * 8) * CD + c0 + tx] = f2f8(t[tx][ty + i * 8]);
}

// fp8 GEMM: C8[m][n] = fp8(sum_k A[m][k]*B[n][k] + bias). 128x128 tile, BK=64,
// 4 waves, dbuf gl_lds16 staging (pre-swizzled source), counted vmcnt.
template<int BIAS_MODE>
__global__ __launch_bounds__(256)
void gemm_bt8(const unsigned char* __restrict__ A,
              const unsigned char* __restrict__ B,
              unsigned char* __restrict__ C8,
              const float* __restrict__ bias,
              int K, int lda, int ldb, int ldc,
              long sA, long sB, long sC)
{
    __shared__ __align__(16) unsigned char As[2][128 * 64];
    __shared__ __align__(16) unsigned char Bs[2][128 * 64];

    const int z = blockIdx.z;
    const unsigned char* Ab = A + (size_t)z * sA + (size_t)blockIdx.y * 128 * lda;
    const unsigned char* Bb = B + (size_t)z * sB + (size_t)blockIdx.x * 128 * ldb;

    const int t = threadIdx.x;
    const int lane = t & 63;
    const int wave = t >> 6;
    const int wr = wave >> 1, wc = wave & 1;
    const int lr = lane & 15, lk = lane >> 4;

    f32x4 acc[4][4] = {};

    const int KT = K >> 6;
    auto stage = [&](int kt, int buf) {
        int k0 = kt << 6;
        #pragma unroll
        for (int i = 0; i < 2; ++i) {
            int rb = i * 64 + wave * 16;
            int row = rb + (lane >> 2);
            int src = (lane & 3) ^ ((row >> 1) & 3);
            gl_lds16(Ab + (size_t)row * lda + k0 + src * 16, &As[buf][rb * 64]);
            gl_lds16(Bb + (size_t)row * ldb + k0 + src * 16, &Bs[buf][rb * 64]);
        }
    };
    stage(0, 0);
    for (int kt = 0; kt < KT; ++kt) {
        int cur = kt & 1;
        if (kt + 1 < KT) {
            stage(kt + 1, cur ^ 1);
            asm volatile("s_waitcnt vmcnt(4)" ::: "memory");
        } else {
            asm volatile("s_waitcnt vmcnt(0)" ::: "memory");
        }
        __builtin_amdgcn_s_barrier();
        const unsigned char* Ac = &As[cur][0];
        const unsigned char* Bc = &Bs[cur][0];
        #pragma unroll
        for (int kk = 0; kk < 2; ++kk) {
            int c16 = kk * 2 + (lk >> 1);
            int half = (lk & 1) * 8;
            i64v af[4], bfr[4];
            #pragma unroll
            for (int f = 0; f < 4; ++f) {
                int arow = wr * 64 + f * 16 + lr;
                af[f] = *(const i64v*)&Ac[arow * 64 + ((c16 ^ ((arow >> 1) & 3)) << 4) + half];
                int brow = wc * 64 + f * 16 + lr;
                bfr[f] = *(const i64v*)&Bc[brow * 64 + ((c16 ^ ((brow >> 1) & 3)) << 4) + half];
            }
            #pragma unroll
            for (int fm = 0; fm < 4; ++fm)
                #pragma unroll
                for (int fn = 0; fn < 4; ++fn)
                    acc[fm][fn] = __builtin_amdgcn_mfma_f32_16x16x32_fp8_fp8(
                        af[fm], bfr[fn], acc[fm][fn], 0, 0, 0);
        }
        asm volatile("s_waitcnt lgkmcnt(0)" ::: "memory");
        __builtin_amdgcn_s_barrier();
    }

    const int m0 = blockIdx.y * 128;
    const int n0 = blockIdx.x * 128;
    unsigned char* Cp = C8 + (size_t)z * sC;
    #pragma unroll
    for (int fm = 0; fm < 4; ++fm) {
        #pragma unroll
        for (int fn = 0; fn < 4; ++fn) {
            int col = n0 + wc * 64 + fn * 16 + lr;          // D col = lane&15
            int rowb = m0 + wr * 64 + fm * 16 + lk * 4;     // D row = 4*(lane>>4)+j
            #pragma unroll
            for (int j = 0; j < 4; ++j) {
                int row = rowb + j;
                float v = acc[fm][fn][j];
                if (BIAS_MODE == 1) v += bias[col];
                if (BIAS_MODE == 2) v += bias[row];
                Cp[(size_t)row * ldc + col] = f2f8(v);
            }
        }
    }
}

// bf16 GEMM (out-projection only): out = Wo*H^T + bo + x, fp32 out.
__global__ __launch_bounds__(256)
void gemm_bt_out(const unsigned short* __restrict__ A,
                 const unsigned short* __restrict__ B,
                 float* __restrict__ Cf,
                 const float* __restrict__ bias,
                 const float* __restrict__ resid,
                 int K, int lda, int ldb, int ldc,
                 long sB, long sC, long sR)
{
    __shared__ __align__(16) unsigned short As[2][128 * 64];
    __shared__ __align__(16) unsigned short Bs[2][128 * 64];

    const int z = blockIdx.z;
    const unsigned short* Ab = A + (size_t)blockIdx.y * 128 * lda;
    const unsigned short* Bb = B + (size_t)z * sB + (size_t)blockIdx.x * 128 * ldb;

    const int t = threadIdx.x;
    const int lane = t & 63;
    const int wave = t >> 6;
    const int wr = wave >> 1, wc = wave & 1;
    const int lr = lane & 15, lk = lane >> 4;

    f32x4 acc[4][4] = {};

    const int KT = K >> 6;
    auto stage = [&](int kt, int buf) {
        int k0 = kt << 6;
        #pragma unroll
        for (int i = 0; i < 4; ++i) {
            int rb = i * 32 + wave * 8;
            int row = rb + (lane >> 3);
            int ch = (lane & 7) ^ (row & 7);
            gl_lds16(Ab + (size_t)row * lda + k0 + ch * 8, &As[buf][rb * 64]);
            gl_lds16(Bb + (size_t)row * ldb + k0 + ch * 8, &Bs[buf][rb * 64]);
        }
    };
    stage(0, 0);
    for (int kt = 0; kt < KT; ++kt) {
        int cur = kt & 1;
        if (kt + 1 < KT) {
            stage(kt + 1, cur ^ 1);
            asm volatile("s_waitcnt vmcnt(8)" ::: "memory");
        } else {
            asm volatile("s_waitcnt vmcnt(0)" ::: "memory");
        }
        __builtin_amdgcn_s_barrier();
        const unsigned short* Ac = &As[cur][0];
        const unsigned short* Bc = &Bs[cur][0];
        #pragma unroll
        for (int kk = 0; kk < 2; ++kk) {
            bf16x8 af[4], bfr[4];
            #pragma unroll
            for (int f = 0; f < 4; ++f) {
                int arow = wr * 64 + f * 16 + lr;
                af[f] = *(const bf16x8*)&Ac[(arow << 6) + ((((kk << 2) | lk) ^ (arow & 7)) << 3)];
                int brow = wc * 64 + f * 16 + lr;
                bfr[f] = *(const bf16x8*)&Bc[(brow << 6) + ((((kk << 2) | lk) ^ (brow & 7)) << 3)];
            }
            #pragma unroll
            for (int fm = 0; fm < 4; ++fm)
                #pragma unroll
                for (int fn = 0; fn < 4; ++fn)
                    acc[fm][fn] = __builtin_amdgcn_mfma_f32_16x16x32_bf16(
                        af[fm], bfr[fn], acc[fm][fn], 0, 0, 0);
        }
        asm volatile("s_waitcnt lgkmcnt(0)" ::: "memory");
        __builtin_amdgcn_s_barrier();
    }

    const int m0 = blockIdx.y * 128;
    const int n0 = blockIdx.x * 128;
    float* Co = Cf + (size_t)z * sC;
    const float* rp = resid + (size_t)z * sR;
    #pragma unroll
    for (int fm = 0; fm < 4; ++fm) {
        #pragma unroll
        for (int fn = 0; fn < 4; ++fn) {
            int col = n0 + wc * 64 + fn * 16 + lr;
            int rowb = m0 + wr * 64 + fm * 16 + lk * 4;
            #pragma unroll
            for (int j = 0; j < 4; ++j) {
                int row = rowb + j;
                float v = acc[fm][fn][j] + bias[row] + rp[(size_t)row * ldc + col];
                Co[(size_t)row * ldc + col] = v;
            }
        }
    }
}

// Fused attention, fp8, role-split producer/consumer. Block = 1 batch x 128 q,
// 12 waves (768 thr): waves 0-3 = QK+softmax (32 q each, Q in regs, swapped
// mfma(K,Q), K-frags shared across the 2 q-halves); waves 4-11 = PV (64-ch
// slice each, all 128 q) + ALL staging (K rows split 8 ways; V own-slice only,
// issued after own reads). kv-tile 64, K/V/P/Ls double-buffered, ONE barrier
// per tile: QK computes tile t+1 while PV consumes tile t.
__global__ __launch_bounds__(768, 3)
void flash_attn(const unsigned char* __restrict__ Q,
                const unsigned char* __restrict__ Kg,
                const unsigned char* __restrict__ Vg,
                unsigned short* __restrict__ H)
{
    __shared__ __align__(16) unsigned char Ks[2][64 * 512];  // 64 KB
    __shared__ __align__(16) unsigned char Vs[2][512 * 64];  // 64 KB
    __shared__ __align__(16) unsigned char Ps[2][128 * 72];  // 18 KB
    __shared__ __align__(16) float Ls[2][128];               // rescale factors
    __shared__ __align__(16) float Lfin[128];                // 1/l epilogue
    __shared__ int flags[2];                                 // rescale epoch

    const int p = blockIdx.x;                // XCD-affinity decode
    const int b  = ((p >> 6) << 3) + (p & 7);
    const int qt = (p >> 3) & 7;

    const int tid = threadIdx.x;
    const int w = tid >> 6, lane = tid & 63;
    const int lr = lane & 15, lk = lane >> 4;

    if (tid == 0) { flags[0] = -1; flags[1] = -1; }

    const unsigned char* Kb = Kg + (size_t)b * NSP * 1024;   // rows 1024B (Q|K)
    const unsigned char* Vb = Vg + (size_t)b * CD * 1024;

    if (w < 4) {
        // ================= QK + softmax role (waves 0-3) =================
        const int q0 = qt * 128 + w * 32;
        i64v qf0[16], qf1[16];
        const unsigned char* qp = Q + ((size_t)b * NSP + q0 + lr) * 1024 + lk * 8;
        #pragma unroll
        for (int st = 0; st < 16; ++st) {
            qf0[st] = *(const i64v*)(qp + st * 32);
            qf1[st] = *(const i64v*)(qp + 16 * 1024 + st * 32);
        }
        float m0 = -3.0e38f, m1 = -3.0e38f, l0 = 0.f, l1 = 0.f;

        auto qksm = [&](int tau) {
            const int pb = tau & 1;
            const unsigned char* Kc = &Ks[pb][0];
            f32x4 s0[4] = {}, s1[4] = {};
            __builtin_amdgcn_s_setprio(1);
            #pragma unroll
            for (int st = 0; st < 16; ++st) {
                int c16 = st * 2 + (lk >> 1);
                int half = (lk & 1) * 8;
                #pragma unroll
                for (int kvf = 0; kvf < 4; ++kvf) {
                    int row = kvf * 16 + lr;
                    i64v kf = *(const i64v*)&Kc[row * 512 + ((c16 ^ (row & 7)) << 4) + half];
                    s0[kvf] = __builtin_amdgcn_mfma_f32_16x16x32_fp8_fp8(kf, qf0[st], s0[kvf], 0, 0, 0);
                    s1[kvf] = __builtin_amdgcn_mfma_f32_16x16x32_fp8_fp8(kf, qf1[st], s1[kvf], 0, 0, 0);
                }
            }
            __builtin_amdgcn_s_setprio(0);
            #pragma unroll
            for (int kvf = 0; kvf < 4; ++kvf)
                #pragma unroll
                for (int j = 0; j < 4; ++j) {
                    s0[kvf][j] *= SCALE_EXP2;
                    s1[kvf][j] *= SCALE_EXP2;
                }
            float pm0 = fmaxf(fmaxf(fmaxf(s0[0][0], s0[0][1]), fmaxf(s0[0][2], s0[0][3])),
                              fmaxf(fmaxf(s0[1][0], s0[1][1]), fmaxf(s0[1][2], s0[1][3])));
            pm0 = fmaxf(pm0, fmaxf(fmaxf(fmaxf(s0[2][0], s0[2][1]), fmaxf(s0[2][2], s0[2][3])),
                                   fmaxf(fmaxf(s0[3][0], s0[3][1]), fmaxf(s0[3][2], s0[3][3]))));
            float pm1 = fmaxf(fmaxf(fmaxf(s1[0][0], s1[0][1]), fmaxf(s1[0][2], s1[0][3])),
                              fmaxf(fmaxf(s1[1][0], s1[1][1]), fmaxf(s1[1][2], s1[1][3])));
            pm1 = fmaxf(pm1, fmaxf(fmaxf(fmaxf(s1[2][0], s1[2][1]), fmaxf(s1[2][2], s1[2][3])),
                                   fmaxf(fmaxf(s1[3][0], s1[3][1]), fmaxf(s1[3][2], s1[3][3]))));
            pm0 = fmaxf(pm0, __shfl_xor(pm0, 16));
            pm0 = fmaxf(pm0, __shfl_xor(pm0, 32));
            pm1 = fmaxf(pm1, __shfl_xor(pm1, 16));
            pm1 = fmaxf(pm1, __shfl_xor(pm1, 32));
            bool ev = !__all(fmaxf(pm0 - m0, pm1 - m1) <= 8.0f);  // defer-max
            float sc0 = 1.f, sc1 = 1.f;
            if (ev) {
                float n0 = fmaxf(m0, pm0); sc0 = exp2f(m0 - n0); m0 = n0; l0 *= sc0;
                float n1 = fmaxf(m1, pm1); sc1 = exp2f(m1 - n1); m1 = n1; l1 *= sc1;
            }
            if (lk == 0) { Ls[pb][w * 32 + lr] = sc0; Ls[pb][w * 32 + 16 + lr] = sc1; }
            if (ev && lane == 0) flags[pb] = tau;
            float rs0 = 0.f, rs1 = 0.f;
            #pragma unroll
            for (int kvf = 0; kvf < 4; ++kvf) {
                #pragma unroll
                for (int j = 0; j < 4; ++j) {
                    s0[kvf][j] = exp2f(s0[kvf][j] - m0); rs0 += s0[kvf][j];
                    s1[kvf][j] = exp2f(s1[kvf][j] - m1); rs1 += s1[kvf][j];
                }
                unsigned int pk0 = f4_to_f8x4(s0[kvf][0], s0[kvf][1], s0[kvf][2], s0[kvf][3]);
                unsigned int pk1 = f4_to_f8x4(s1[kvf][0], s1[kvf][1], s1[kvf][2], s1[kvf][3]);
                *(unsigned int*)&Ps[pb][(w * 32 + lr) * 72 + kvf * 16 + lk * 4] = pk0;
                *(unsigned int*)&Ps[pb][(w * 32 + 16 + lr) * 72 + kvf * 16 + lk * 4] = pk1;
            }
            rs0 += __shfl_xor(rs0, 16); rs0 += __shfl_xor(rs0, 32); l0 += rs0;
            rs1 += __shfl_xor(rs1, 16); rs1 += __shfl_xor(rs1, 32); l1 += rs1;
        };

        __builtin_amdgcn_s_barrier();                        // b1: K0/V0 landed
        qksm(0);
        asm volatile("s_waitcnt lgkmcnt(0)" ::: "memory");
        __builtin_amdgcn_s_barrier();                        // b2: P(0) ready
        for (int t = 0; t < 16; ++t) {
            if (t < 15) qksm(t + 1);                         // K(t+1) landed via prev barrier
            asm volatile("s_waitcnt lgkmcnt(0)" ::: "memory");
            __builtin_amdgcn_s_barrier();
        }
        if (lk == 0) { Lfin[w * 32 + lr] = 1.f / l0; Lfin[w * 32 + 16 + lr] = 1.f / l1; }
        asm volatile("s_waitcnt lgkmcnt(0)" ::: "memory");
        __builtin_amdgcn_s_barrier();                        // b_fin
    } else {
        // ================= PV + staging role (waves 4-11) =================
        const int wp = w - 4;
        auto stageK = [&](int t, int buf) {                  // 4 calls = 8 rows
            int kv0 = t * 64;
            #pragma unroll
            for (int i = 0; i < 4; ++i) {
                int rb = i * 16 + wp * 2;
                int row = rb + (lane >> 5);
                int src = (lane & 31) ^ (row & 7);
                gl_lds16(Kb + (size_t)(kv0 + row) * 1024 + src * 16, &Ks[buf][rb * 512]);
            }
        };
        auto stageV = [&](int t, int buf) {                  // own 64-ch slice
            int kv0 = t * 64;
            #pragma unroll
            for (int i = 0; i < 4; ++i) {
                int cb = wp * 64 + i * 16;
                int c = cb + (lane >> 2);
                int src = (lane & 3) ^ ((c >> 1) & 3);
                gl_lds16(Vb + (size_t)c * 1024 + kv0 + src * 16, &Vs[buf][cb * 64]);
            }
        };
        f32x4 o[8][4] = {};      // [qf2][cf]: q = qf2*16+4lk+j, c = wp*64+cf*16+lr

        stageK(0, 0); stageV(0, 0);
        asm volatile("s_waitcnt vmcnt(0)" ::: "memory");
        __builtin_amdgcn_s_barrier();                        // b1
        stageK(1, 1); stageV(1, 1);
        asm volatile("s_waitcnt vmcnt(0)" ::: "memory");
        __builtin_amdgcn_s_barrier();                        // b2

        for (int t = 0; t < 16; ++t) {
            const int pb = t & 1;
            if (t < 14) stageK(t + 2, pb);                   // K(t) reads done prev iter
            if (flags[pb] == t) {
                #pragma unroll
                for (int qf2 = 0; qf2 < 8; ++qf2) {
                    f32x4 scv = *(const f32x4*)&Ls[pb][qf2 * 16 + lk * 4];
                    #pragma unroll
                    for (int cf = 0; cf < 4; ++cf) {
                        o[qf2][cf][0] *= scv[0]; o[qf2][cf][1] *= scv[1];
                        o[qf2][cf][2] *= scv[2]; o[qf2][cf][3] *= scv[3];
                    }
                }
            }
            const unsigned char* Vc = &Vs[pb][0];
            __builtin_amdgcn_s_setprio(1);
            #pragma unroll
            for (int ks = 0; ks < 2; ++ks) {
                int c16 = ks * 2 + (lk >> 1);
                int half = (lk & 1) * 8;
                i64v vfr[4];
                #pragma unroll
                for (int cf = 0; cf < 4; ++cf) {
                    int c = wp * 64 + cf * 16 + lr;
                    vfr[cf] = *(const i64v*)&Vc[c * 64 + ((c16 ^ ((c >> 1) & 3)) << 4) + half];
                }
                #pragma unroll
                for (int qf2 = 0; qf2 < 8; ++qf2) {
                    i64v pa = *(const i64v*)&Ps[pb][(qf2 * 16 + lr) * 72 + ks * 32 + lk * 8];
                    #pragma unroll
                    for (int cf = 0; cf < 4; ++cf)
                        o[qf2][cf] = __builtin_amdgcn_mfma_f32_16x16x32_fp8_fp8(
                            pa, vfr[cf], o[qf2][cf], 0, 0, 0);
                }
            }
            __builtin_amdgcn_s_setprio(0);
            asm volatile("s_waitcnt lgkmcnt(0)" ::: "memory");  // own V reads done
            if (t < 14) {
                stageV(t + 2, pb);                           // own slice only
                asm volatile("s_waitcnt vmcnt(4)" ::: "memory"); // drains V(t+1)+K(t+2)
            } else {
                asm volatile("s_waitcnt vmcnt(0)" ::: "memory");
            }
            __builtin_amdgcn_s_barrier();
        }
        __builtin_amdgcn_s_barrier();                        // b_fin: Lfin ready
        unsigned short* Hp = H + ((size_t)b * NSP + qt * 128) * CD + wp * 64;
        #pragma unroll
        for (int qf2 = 0; qf2 < 8; ++qf2) {
            f32x4 li = *(const f32x4*)&Lfin[qf2 * 16 + lk * 4];
            #pragma unroll
            for (int cf = 0; cf < 4; ++cf) {
                #pragma unroll
                for (int j = 0; j < 4; ++j)
                    Hp[(size_t)(qf2 * 16 + lk * 4 + j) * CD + cf * 16 + lr] =
                        f2bf(o[qf2][cf][j] * li[j]);
            }
        }
    }
}

extern "C" void kernel_launch(void* const* d_in, const int* in_sizes, int n_in,
                              void* d_out, int out_size, void* d_ws, size_t ws_size,
                              hipStream_t stream)
{
    const float* x  = (const float*)d_in[0];
    const float* Wq = (const float*)d_in[1];
    const float* bq = (const float*)d_in[2];
    const float* Wk = (const float*)d_in[3];
    const float* bk = (const float*)d_in[4];
    const float* Wv = (const float*)d_in[5];
    const float* bv = (const float*)d_in[6];
    const float* Wo = (const float*)d_in[7];
    const float* bo = (const float*)d_in[8];
    float* out = (float*)d_out;

    unsigned char* w = (unsigned char*)d_ws;   // byte layout, all 16B-aligned
    unsigned char*  W8  = w;                            // Wq|Wk|Wv fp8, 786432 B
    unsigned short* Wob = (unsigned short*)(w + 786432);        // bf16, 524288 B
    float*          bqk = (float*)(w + 1310720);                // 4096 B
    unsigned char*  Xt8 = w + 1314816;                          // [B][N][C] fp8
    unsigned char*  QK8 = w + 18092032;                         // [B][N][1024] fp8
    unsigned char*  Vc8 = w + 51646464;                         // [B][C][N] fp8
    unsigned short* Hb  = (unsigned short*)(w + 68423680);      // [B][N][C] bf16

    cvt_all<<<4096, 256, 0, stream>>>(Wq, Wk, Wv, Wo, bq, bk, W8, Wob, bqk);
    transpose_x<<<dim3(32, 16, 32), dim3(32, 8), 0, stream>>>(x, Xt8);

    // QK = Xt * [Wq;Wk]^T + [bq;bk]   [32768 x 1024] fp8
    gemm_bt8<1><<<dim3(8, 256, 1), 256, 0, stream>>>(
        Xt8, W8, QK8, bqk, 512, 512, 512, 1024, 0, 0, 0);

    // V in [C][N] fp8: A=Wv fp8, B=Xt_b, bias per-row(c)
    gemm_bt8<2><<<dim3(8, 4, 32), 256, 0, stream>>>(
        W8 + 524288, Xt8, Vc8, bv, 512, 512, 512, 1024, 0, 524288, 524288);

    // fused attention -> Hb [B][N][C] bf16
    flash_attn<<<256, 768, 0, stream>>>(QK8, QK8 + 512, Vc8, Hb);

    // out = Wo * H_b^T + bo(row) + x   [C][N] fp32 (bf16 gemm)
    gemm_bt_out<<<dim3(8, 4, 32), 256, 0, stream>>>(
        Wob, Hb, out, bo, x, 512, 512, 512, 1024, 524288, 524288, 524288);
}

// Round 11
// 211.359 us; speedup vs baseline: 1.0067x; 1.0067x over previous
//
#include <hip/hip_runtime.h>
#include <stdint.h>

// AttentionBlock: B=32, C=512, H=W=32 (N=1024), fp32 in/out.
//   cvt: Wq,Wk,Wv -> fp8 e4m3; Wo -> fp8 scaled by 2^22; bqk=[bq;bk] f32
//   transpose x -> Xt [B,N,C] fp8
//   QK = Xt*[Wq;Wk]^T + [bq;bk]  [B*N,1024] fp8 (Q cols 0-511, K 512-1023)
//   V  = Wv*Xt_b^T + bv          [B][C][N] fp8
//   H  = flash_attn fp8 (kv32, dbuf, 4-wave blocks, grid 512 = 2 blocks/CU)
//   out = (Wo*2^22)*H_b^T * 2^-22 + bo + x   [B][C][N] fp32 (fp8 gemm)

#define CD 512
#define NSP 1024
#define SCALE_EXP2 0.06376339f   // C^-0.5 * log2(e)
#define WO_SCALE 4194304.0f      // 2^22
#define WO_INV   2.384185791015625e-7f

using bf16x8 = __attribute__((ext_vector_type(8))) short;
using f32x4  = __attribute__((ext_vector_type(4))) float;
typedef long i64v;               // 8 x fp8 operand for MFMA

__device__ __forceinline__ unsigned char f2f8(float f) {
    unsigned int r;
    asm("v_cvt_pk_fp8_f32 %0, %1, %1" : "=v"(r) : "v"(f));
    return (unsigned char)(r & 0xffu);
}
__device__ __forceinline__ unsigned int f4_to_f8x4(float a, float b, float c, float d) {
    unsigned int r = 0;
    asm("v_cvt_pk_fp8_f32 %0, %2, %3\n\t"
        "v_cvt_pk_fp8_f32 %0, %4, %5 op_sel:[0,0,1]"
        : "=v"(r) : "0"(r), "v"(a), "v"(b), "v"(c), "v"(d));
    return r;
}
__device__ __forceinline__ void gl_lds16(const void* g, void* l) {
    __builtin_amdgcn_global_load_lds(
        (const __attribute__((address_space(1))) void*)g,
        (__attribute__((address_space(3))) void*)l, 16, 0, 0);
}

// Wq,Wk,Wv,Wo -> fp8 (contiguous [4*512][512]; Wo scaled 2^22); bqk concat f32
__global__ __launch_bounds__(256) void cvt_all(
    const float* __restrict__ Wq, const float* __restrict__ Wk,
    const float* __restrict__ Wv, const float* __restrict__ Wo,
    const float* __restrict__ bq, const float* __restrict__ bk,
    unsigned char* __restrict__ w8, float* __restrict__ bqk)
{
    int idx = blockIdx.x * 256 + threadIdx.x;     // 0..1048575
    int which = idx >> 18, off = idx & 262143;
    const float* src = which == 0 ? Wq : which == 1 ? Wk : which == 2 ? Wv : Wo;
    float v = src[off] * (which == 3 ? WO_SCALE : 1.0f);
    w8[idx] = f2f8(v);
    if (idx < 1024) bqk[idx] = (idx < 512) ? bq[idx] : bk[idx - 512];
}

// x [B][C][N] f32 -> xt [B][N][C] fp8
__global__ __launch_bounds__(256) void transpose_x(const float* __restrict__ x,
                                                   unsigned char* __restrict__ xt) {
    __shared__ float t[32][33];
    int b = blockIdx.z;
    int n0 = blockIdx.x * 32, c0 = blockIdx.y * 32;
    const float* xb = x + (size_t)b * CD * NSP;
    unsigned char* xtb = xt + (size_t)b * NSP * CD;
    int tx = threadIdx.x, ty = threadIdx.y;
    #pragma unroll
    for (int i = 0; i < 4; ++i)
        t[ty + i * 8][tx] = xb[(size_t)(c0 + ty + i * 8) * NSP + n0 + tx];
    __syncthreads();
    #pragma unroll
    for (int i = 0; i < 4; ++i)
        xtb[(size_t)(n0 + ty + i * 8) * CD + c0 + tx] = f2f8(t[tx][ty + i * 8]);
}

// fp8 GEMM: C[m][n] = alpha*sum_k A[m][k]*B[n][k] (+bias) (+resid).
// 128x128 tile, BK=64, 4 waves, dbuf gl_lds16 staging, counted vmcnt.
// Output fp8 or f32 per OUT_F32.
template<int BIAS_MODE, bool RESID, bool OUT_F32>
__global__ __launch_bounds__(256)
void gemm_bt8(const unsigned char* __restrict__ A,
              const unsigned char* __restrict__ B,
              void* __restrict__ Cv,
              const float* __restrict__ bias,
              const float* __restrict__ resid,
              int K, int lda, int ldb, int ldc,
              long sA, long sB, long sC, long sR, float alpha)
{
    __shared__ __align__(16) unsigned char As[2][128 * 64];
    __shared__ __align__(16) unsigned char Bs[2][128 * 64];

    const int z = blockIdx.z;
    const unsigned char* Ab = A + (size_t)z * sA + (size_t)blockIdx.y * 128 * lda;
    const unsigned char* Bb = B + (size_t)z * sB + (size_t)blockIdx.x * 128 * ldb;

    const int t = threadIdx.x;
    const int lane = t & 63;
    const int wave = t >> 6;
    const int wr = wave >> 1, wc = wave & 1;
    const int lr = lane & 15, lk = lane >> 4;

    f32x4 acc[4][4] = {};

    const int KT = K >> 6;
    auto stage = [&](int kt, int buf) {
        int k0 = kt << 6;
        #pragma unroll
        for (int i = 0; i < 2; ++i) {
            int rb = i * 64 + wave * 16;
            int row = rb + (lane >> 2);
            int src = (lane & 3) ^ ((row >> 1) & 3);
            gl_lds16(Ab + (size_t)row * lda + k0 + src * 16, &As[buf][rb * 64]);
            gl_lds16(Bb + (size_t)row * ldb + k0 + src * 16, &Bs[buf][rb * 64]);
        }
    };
    stage(0, 0);
    for (int kt = 0; kt < KT; ++kt) {
        int cur = kt & 1;
        if (kt + 1 < KT) {
            stage(kt + 1, cur ^ 1);
            asm volatile("s_waitcnt vmcnt(4)" ::: "memory");
        } else {
            asm volatile("s_waitcnt vmcnt(0)" ::: "memory");
        }
        __builtin_amdgcn_s_barrier();
        const unsigned char* Ac = &As[cur][0];
        const unsigned char* Bc = &Bs[cur][0];
        #pragma unroll
        for (int kk = 0; kk < 2; ++kk) {
            int c16 = kk * 2 + (lk >> 1);
            int half = (lk & 1) * 8;
            i64v af[4], bfr[4];
            #pragma unroll
            for (int f = 0; f < 4; ++f) {
                int arow = wr * 64 + f * 16 + lr;
                af[f] = *(const i64v*)&Ac[arow * 64 + ((c16 ^ ((arow >> 1) & 3)) << 4) + half];
                int brow = wc * 64 + f * 16 + lr;
                bfr[f] = *(const i64v*)&Bc[brow * 64 + ((c16 ^ ((brow >> 1) & 3)) << 4) + half];
            }
            #pragma unroll
            for (int fm = 0; fm < 4; ++fm)
                #pragma unroll
                for (int fn = 0; fn < 4; ++fn)
                    acc[fm][fn] = __builtin_amdgcn_mfma_f32_16x16x32_fp8_fp8(
                        af[fm], bfr[fn], acc[fm][fn], 0, 0, 0);
        }
        asm volatile("s_waitcnt lgkmcnt(0)" ::: "memory");
        __builtin_amdgcn_s_barrier();
    }

    const int m0 = blockIdx.y * 128;
    const int n0 = blockIdx.x * 128;
    unsigned char* C8 = (unsigned char*)Cv + (size_t)z * sC;
    float* Cf = (float*)Cv + (size_t)z * sC;
    const float* rp = RESID ? resid + (size_t)z * sR : nullptr;
    #pragma unroll
    for (int fm = 0; fm < 4; ++fm) {
        #pragma unroll
        for (int fn = 0; fn < 4; ++fn) {
            int col = n0 + wc * 64 + fn * 16 + lr;          // D col = lane&15
            int rowb = m0 + wr * 64 + fm * 16 + lk * 4;     // D row = 4*(lane>>4)+j
            #pragma unroll
            for (int j = 0; j < 4; ++j) {
                int row = rowb + j;
                float v = acc[fm][fn][j] * alpha;
                if (BIAS_MODE == 1) v += bias[col];
                if (BIAS_MODE == 2) v += bias[row];
                if (RESID) v += rp[(size_t)row * ldc + col];
                if (OUT_F32) Cf[(size_t)row * ldc + col] = v;
                else         C8[(size_t)row * ldc + col] = f2f8(v);
            }
        }
    }
}

// Fused attention, fp8, kv-tile 32, K/V double-buffered, 2 barriers/tile.
// Block = 64 q-rows x 4 waves (256 thr), grid 512 -> 2 independent blocks/CU
// (two barrier domains overlap QK/softmax/PV phases across blocks).
// QK^T: wave w owns q [w*16,w*16+16) (Q fp8 in regs, swapped mfma(K,Q), scale
// on S in f32). P fp8 -> block LDS (pitch 40B). PV c-split: wave w owns
// channels [w*128,(w+1)*128) for all 64 q. H written fp8.
__global__ __launch_bounds__(256, 2)
void flash_attn(const unsigned char* __restrict__ Q,
                const unsigned char* __restrict__ Kg,
                const unsigned char* __restrict__ Vg,
                unsigned char* __restrict__ H)
{
    __shared__ __align__(16) unsigned char Ks[2][32 * 512];  // 32 KB
    __shared__ __align__(16) unsigned char Vs[2][512 * 32];  // 32 KB
    __shared__ __align__(16) unsigned char Ps[64 * 40];      // 2.5 KB
    __shared__ __align__(16) float Ls[64];
    __shared__ int flag;                                     // rescale epoch

    const int p = blockIdx.x;                // 512 blocks; p&7 = XCD affinity
    const int b  = (p & 7) + 8 * (p >> 7);   // 4 batches per XCD
    const int qt = (p >> 3) & 15;            // 16 q-tiles of 64 rows

    const int tid = threadIdx.x;
    const int w = tid >> 6, lane = tid & 63;
    const int lr = lane & 15, lk = lane >> 4;
    const int q0 = qt * 64 + w * 16;

    // Q frags (B-operand): lane holds Q[q0+lr][st*32 + lk*8 + e], fp8
    i64v qf[16];
    const unsigned char* qp = Q + ((size_t)b * NSP + q0 + lr) * 1024 + lk * 8;
    #pragma unroll
    for (int st = 0; st < 16; ++st) qf[st] = *(const i64v*)(qp + st * 32);

    f32x4 o[4][8] = {};      // [qf2][cf]: q = qf2*16+4lk+j, c = w*128+cf*16+lr
    float m = -3.0e38f, l = 0.f;

    const unsigned char* Kb = Kg + (size_t)b * NSP * 1024;   // rows 1024B (Q|K)
    const unsigned char* Vb = Vg + (size_t)b * CD * 1024;

    auto stageK = [&](int t, int buf) {      // 32 rows x 512B, 8 rows/wave
        int kv0 = t * 32;
        #pragma unroll
        for (int i = 0; i < 4; ++i) {
            int rb = w * 8 + i * 2;
            int row = rb + (lane >> 5);
            int src = (lane & 31) ^ (row & 7);
            gl_lds16(Kb + (size_t)(kv0 + row) * 1024 + src * 16, &Ks[buf][rb * 512]);
        }
    };
    auto stageV = [&](int t, int buf) {      // own 128-ch slice, rows 32B
        int kv0 = t * 32;
        #pragma unroll
        for (int i = 0; i < 4; ++i) {
            int cb = w * 128 + i * 32;
            int c = cb + (lane >> 1);
            int srch = (lane & 1) ^ (c & 1);
            gl_lds16(Vb + (size_t)c * 1024 + kv0 + srch * 16, &Vs[buf][cb * 32]);
        }
    };

    if (tid == 0) flag = -1;
    stageK(0, 0); stageV(0, 0);
    asm volatile("s_waitcnt vmcnt(0) lgkmcnt(0)" ::: "memory");
    __builtin_amdgcn_s_barrier();

    for (int t = 0; t < 32; ++t) {
        const int cur = t & 1;
        if (t < 31) { stageK(t + 1, cur ^ 1); stageV(t + 1, cur ^ 1); }

        // ---- QK^T: S^T[kv][q=lr], kv = kvf*16 + 4lk + j ----
        f32x4 s[2] = {};
        const unsigned char* Kc = &Ks[cur][0];
        __builtin_amdgcn_s_setprio(1);
        #pragma unroll
        for (int st = 0; st < 16; ++st) {
            int c16 = st * 2 + (lk >> 1);
            int half = (lk & 1) * 8;
            #pragma unroll
            for (int kvf = 0; kvf < 2; ++kvf) {
                int row = kvf * 16 + lr;
                i64v kf = *(const i64v*)&Kc[row * 512 + ((c16 ^ (row & 7)) << 4) + half];
                s[kvf] = __builtin_amdgcn_mfma_f32_16x16x32_fp8_fp8(kf, qf[st], s[kvf], 0, 0, 0);
            }
        }
        __builtin_amdgcn_s_setprio(0);

        // ---- scale + online softmax (exp2 domain), q = lr ----
        #pragma unroll
        for (int kvf = 0; kvf < 2; ++kvf)
            #pragma unroll
            for (int j = 0; j < 4; ++j) s[kvf][j] *= SCALE_EXP2;

        float pm = fmaxf(fmaxf(fmaxf(s[0][0], s[0][1]), fmaxf(s[0][2], s[0][3])),
                         fmaxf(fmaxf(s[1][0], s[1][1]), fmaxf(s[1][2], s[1][3])));
        pm = fmaxf(pm, __shfl_xor(pm, 16));
        pm = fmaxf(pm, __shfl_xor(pm, 32));
        bool ev = !__all(pm - m <= 8.0f);       // defer-max: P <= 2^8 < 448
        float mn = fmaxf(m, pm);
        float sc = ev ? exp2f(m - mn) : 1.0f;
        if (ev) { m = mn; l *= sc; }
        if (lk == 0) Ls[w * 16 + lr] = sc;
        if (ev && lane == 0) flag = t;          // epoch flag

        float rs = 0.f;
        #pragma unroll
        for (int kvf = 0; kvf < 2; ++kvf)
            #pragma unroll
            for (int j = 0; j < 4; ++j) {
                s[kvf][j] = exp2f(s[kvf][j] - m);
                rs += s[kvf][j];
            }
        rs += __shfl_xor(rs, 16);
        rs += __shfl_xor(rs, 32);
        l += rs;

        // pack P fp8 -> Ps[q = w*16+lr][kv] (u32 writes, pitch 40B)
        #pragma unroll
        for (int kvf = 0; kvf < 2; ++kvf) {
            unsigned int pk = f4_to_f8x4(s[kvf][0], s[kvf][1], s[kvf][2], s[kvf][3]);
            *(unsigned int*)&Ps[(w * 16 + lr) * 40 + kvf * 16 + lk * 4] = pk;
        }
        asm volatile("s_waitcnt lgkmcnt(0)" ::: "memory");
        __builtin_amdgcn_s_barrier();                       // B1: P/Ls/flag visible

        // ---- PV: wave owns c-slice [w*128, w*128+128) for all 64 q ----
        if (flag == t) {
            #pragma unroll
            for (int qf2 = 0; qf2 < 4; ++qf2) {
                f32x4 scv = *(const f32x4*)&Ls[qf2 * 16 + lk * 4];
                #pragma unroll
                for (int cf = 0; cf < 8; ++cf) {
                    o[qf2][cf][0] *= scv[0]; o[qf2][cf][1] *= scv[1];
                    o[qf2][cf][2] *= scv[2]; o[qf2][cf][3] *= scv[3];
                }
            }
        }
        const unsigned char* Vc = &Vs[cur][0];
        i64v vfr[8];
        #pragma unroll
        for (int cf = 0; cf < 8; ++cf) {
            int c = w * 128 + cf * 16 + lr;
            vfr[cf] = *(const i64v*)&Vc[c * 32 + (((lk >> 1) ^ (c & 1)) << 4) + (lk & 1) * 8];
        }
        __builtin_amdgcn_s_setprio(1);
        #pragma unroll
        for (int qf2 = 0; qf2 < 4; ++qf2) {
            i64v pa = *(const i64v*)&Ps[(qf2 * 16 + lr) * 40 + lk * 8];
            #pragma unroll
            for (int cf = 0; cf < 8; ++cf)
                o[qf2][cf] = __builtin_amdgcn_mfma_f32_16x16x32_fp8_fp8(
                    pa, vfr[cf], o[qf2][cf], 0, 0, 0);
        }
        __builtin_amdgcn_s_setprio(0);
        asm volatile("s_waitcnt vmcnt(0) lgkmcnt(0)" ::: "memory");
        __builtin_amdgcn_s_barrier();                       // B2: buffers swappable
    }

    // epilogue: 1/l per q-row via Ls, write H fp8
    if (lk == 0) Ls[w * 16 + lr] = 1.0f / l;
    asm volatile("s_waitcnt lgkmcnt(0)" ::: "memory");
    __builtin_amdgcn_s_barrier();
    unsigned char* Hp = H + ((size_t)b * NSP + qt * 64) * CD + w * 128;
    #pragma unroll
    for (int qf2 = 0; qf2 < 4; ++qf2) {
        f32x4 li = *(const f32x4*)&Ls[qf2 * 16 + lk * 4];
        #pragma unroll
        for (int cf = 0; cf < 8; ++cf) {
            #pragma unroll
            for (int j = 0; j < 4; ++j)
                Hp[(size_t)(qf2 * 16 + lk * 4 + j) * CD + cf * 16 + lr] =
                    f2f8(o[qf2][cf][j] * li[j]);
        }
    }
}

extern "C" void kernel_launch(void* const* d_in, const int* in_sizes, int n_in,
                              void* d_out, int out_size, void* d_ws, size_t ws_size,
                              hipStream_t stream)
{
    const float* x  = (const float*)d_in[0];
    const float* Wq = (const float*)d_in[1];
    const float* bq = (const float*)d_in[2];
    const float* Wk = (const float*)d_in[3];
    const float* bk = (const float*)d_in[4];
    const float* Wv = (const float*)d_in[5];
    const float* bv = (const float*)d_in[6];
    const float* Wo = (const float*)d_in[7];
    const float* bo = (const float*)d_in[8];
    float* out = (float*)d_out;

    unsigned char* w = (unsigned char*)d_ws;   // byte layout, 16B-aligned
    unsigned char* W8  = w;                     // Wq|Wk|Wv|Wo(x2^22) fp8, 1 MB
    float*         bqk = (float*)(w + 1048576); // 4 KB
    unsigned char* Xt8 = w + 1052672;           // [B][N][C] fp8, 16 MB
    unsigned char* QK8 = w + 17829888;          // [B][N][1024] fp8, 32 MB
    unsigned char* Vc8 = w + 51384320;          // [B][C][N] fp8, 16 MB
    unsigned char* H8  = w + 68161536;          // [B][N][C] fp8, 16 MB

    cvt_all<<<4096, 256, 0, stream>>>(Wq, Wk, Wv, Wo, bq, bk, W8, bqk);
    transpose_x<<<dim3(32, 16, 32), dim3(32, 8), 0, stream>>>(x, Xt8);

    // QK = Xt * [Wq;Wk]^T + [bq;bk]   [32768 x 1024] fp8
    gemm_bt8<1, false, false><<<dim3(8, 256, 1), 256, 0, stream>>>(
        Xt8, W8, QK8, bqk, nullptr, 512, 512, 512, 1024, 0, 0, 0, 0, 1.0f);

    // V in [C][N] fp8: A=Wv fp8, B=Xt_b, bias per-row(c)
    gemm_bt8<2, false, false><<<dim3(8, 4, 32), 256, 0, stream>>>(
        W8 + 524288, Xt8, Vc8, bv, nullptr, 512, 512, 512, 1024,
        0, 524288, 524288, 0, 1.0f);

    // fused attention -> H8 [B][N][C] fp8
    flash_attn<<<512, 256, 0, stream>>>(QK8, QK8 + 512, Vc8, H8);

    // out = (Wo*2^22) * H_b^T * 2^-22 + bo(row) + x   [C][N] fp32
    gemm_bt8<2, true, true><<<dim3(8, 4, 32), 256, 0, stream>>>(
        W8 + 786432, H8, out, bo, x, 512, 512, 512, 1024,
        0, 524288, 524288, 524288, WO_INV);
}

// Round 12
// 196.931 us; speedup vs baseline: 1.0805x; 1.0733x over previous
//
#include <hip/hip_runtime.h>
#include <stdint.h>

// AttentionBlock: B=32, C=512, H=W=32 (N=1024), fp32 in/out.
//   cvt: Wq,Wk,Wv -> fp8 e4m3; Wo -> fp8 scaled by 2^22; bqk=[bq;bk] f32
//   transpose x -> Xt [B,N,C] fp8
//   QK = Xt*[Wq;Wk]^T + [bq;bk]  [B*N,1024] fp8 (Q cols 0-511, K 512-1023)
//   V  = Wv*Xt_b^T + bv          [B][C][N] fp8
//   H  = flash_attn fp8 (kv64, 8 waves, fused PV(t)||QK(t+1), 1 barrier/tile)
//   out = (Wo*2^22)*H_b^T * 2^-22 + bo + x   [B][C][N] fp32 (fp8 gemm)

#define CD 512
#define NSP 1024
#define SCALE_EXP2 0.06376339f   // C^-0.5 * log2(e)
#define WO_SCALE 4194304.0f      // 2^22
#define WO_INV   2.384185791015625e-7f

using bf16x8 = __attribute__((ext_vector_type(8))) short;
using f32x4  = __attribute__((ext_vector_type(4))) float;
typedef long i64v;               // 8 x fp8 operand for MFMA

__device__ __forceinline__ unsigned char f2f8(float f) {
    unsigned int r;
    asm("v_cvt_pk_fp8_f32 %0, %1, %1" : "=v"(r) : "v"(f));
    return (unsigned char)(r & 0xffu);
}
__device__ __forceinline__ unsigned int f4_to_f8x4(float a, float b, float c, float d) {
    unsigned int r = 0;
    asm("v_cvt_pk_fp8_f32 %0, %2, %3\n\t"
        "v_cvt_pk_fp8_f32 %0, %4, %5 op_sel:[0,0,1]"
        : "=v"(r) : "0"(r), "v"(a), "v"(b), "v"(c), "v"(d));
    return r;
}
__device__ __forceinline__ void gl_lds16(const void* g, void* l) {
    __builtin_amdgcn_global_load_lds(
        (const __attribute__((address_space(1))) void*)g,
        (__attribute__((address_space(3))) void*)l, 16, 0, 0);
}

// Wq,Wk,Wv,Wo -> fp8 (contiguous [4*512][512]; Wo scaled 2^22); bqk concat f32
__global__ __launch_bounds__(256) void cvt_all(
    const float* __restrict__ Wq, const float* __restrict__ Wk,
    const float* __restrict__ Wv, const float* __restrict__ Wo,
    const float* __restrict__ bq, const float* __restrict__ bk,
    unsigned char* __restrict__ w8, float* __restrict__ bqk)
{
    int idx = blockIdx.x * 256 + threadIdx.x;     // 0..1048575
    int which = idx >> 18, off = idx & 262143;
    const float* src = which == 0 ? Wq : which == 1 ? Wk : which == 2 ? Wv : Wo;
    float v = src[off] * (which == 3 ? WO_SCALE : 1.0f);
    w8[idx] = f2f8(v);
    if (idx < 1024) bqk[idx] = (idx < 512) ? bq[idx] : bk[idx - 512];
}

// x [B][C][N] f32 -> xt [B][N][C] fp8
__global__ __launch_bounds__(256) void transpose_x(const float* __restrict__ x,
                                                   unsigned char* __restrict__ xt) {
    __shared__ float t[32][33];
    int b = blockIdx.z;
    int n0 = blockIdx.x * 32, c0 = blockIdx.y * 32;
    const float* xb = x + (size_t)b * CD * NSP;
    unsigned char* xtb = xt + (size_t)b * NSP * CD;
    int tx = threadIdx.x, ty = threadIdx.y;
    #pragma unroll
    for (int i = 0; i < 4; ++i)
        t[ty + i * 8][tx] = xb[(size_t)(c0 + ty + i * 8) * NSP + n0 + tx];
    __syncthreads();
    #pragma unroll
    for (int i = 0; i < 4; ++i)
        xtb[(size_t)(n0 + ty + i * 8) * CD + c0 + tx] = f2f8(t[tx][ty + i * 8]);
}

// fp8 GEMM: C[m][n] = alpha*sum_k A[m][k]*B[n][k] (+bias) (+resid).
// 128x128 tile, BK=64, 4 waves, dbuf gl_lds16 staging, counted vmcnt.
template<int BIAS_MODE, bool RESID, bool OUT_F32>
__global__ __launch_bounds__(256)
void gemm_bt8(const unsigned char* __restrict__ A,
              const unsigned char* __restrict__ B,
              void* __restrict__ Cv,
              const float* __restrict__ bias,
              const float* __restrict__ resid,
              int K, int lda, int ldb, int ldc,
              long sA, long sB, long sC, long sR, float alpha)
{
    __shared__ __align__(16) unsigned char As[2][128 * 64];
    __shared__ __align__(16) unsigned char Bs[2][128 * 64];

    const int z = blockIdx.z;
    const unsigned char* Ab = A + (size_t)z * sA + (size_t)blockIdx.y * 128 * lda;
    const unsigned char* Bb = B + (size_t)z * sB + (size_t)blockIdx.x * 128 * ldb;

    const int t = threadIdx.x;
    const int lane = t & 63;
    const int wave = t >> 6;
    const int wr = wave >> 1, wc = wave & 1;
    const int lr = lane & 15, lk = lane >> 4;

    f32x4 acc[4][4] = {};

    const int KT = K >> 6;
    auto stage = [&](int kt, int buf) {
        int k0 = kt << 6;
        #pragma unroll
        for (int i = 0; i < 2; ++i) {
            int rb = i * 64 + wave * 16;
            int row = rb + (lane >> 2);
            int src = (lane & 3) ^ ((row >> 1) & 3);
            gl_lds16(Ab + (size_t)row * lda + k0 + src * 16, &As[buf][rb * 64]);
            gl_lds16(Bb + (size_t)row * ldb + k0 + src * 16, &Bs[buf][rb * 64]);
        }
    };
    stage(0, 0);
    for (int kt = 0; kt < KT; ++kt) {
        int cur = kt & 1;
        if (kt + 1 < KT) {
            stage(kt + 1, cur ^ 1);
            asm volatile("s_waitcnt vmcnt(4)" ::: "memory");
        } else {
            asm volatile("s_waitcnt vmcnt(0)" ::: "memory");
        }
        __builtin_amdgcn_s_barrier();
        const unsigned char* Ac = &As[cur][0];
        const unsigned char* Bc = &Bs[cur][0];
        #pragma unroll
        for (int kk = 0; kk < 2; ++kk) {
            int c16 = kk * 2 + (lk >> 1);
            int half = (lk & 1) * 8;
            i64v af[4], bfr[4];
            #pragma unroll
            for (int f = 0; f < 4; ++f) {
                int arow = wr * 64 + f * 16 + lr;
                af[f] = *(const i64v*)&Ac[arow * 64 + ((c16 ^ ((arow >> 1) & 3)) << 4) + half];
                int brow = wc * 64 + f * 16 + lr;
                bfr[f] = *(const i64v*)&Bc[brow * 64 + ((c16 ^ ((brow >> 1) & 3)) << 4) + half];
            }
            #pragma unroll
            for (int fm = 0; fm < 4; ++fm)
                #pragma unroll
                for (int fn = 0; fn < 4; ++fn)
                    acc[fm][fn] = __builtin_amdgcn_mfma_f32_16x16x32_fp8_fp8(
                        af[fm], bfr[fn], acc[fm][fn], 0, 0, 0);
        }
        asm volatile("s_waitcnt lgkmcnt(0)" ::: "memory");
        __builtin_amdgcn_s_barrier();
    }

    const int m0 = blockIdx.y * 128;
    const int n0 = blockIdx.x * 128;
    unsigned char* C8 = (unsigned char*)Cv + (size_t)z * sC;
    float* Cf = (float*)Cv + (size_t)z * sC;
    const float* rp = RESID ? resid + (size_t)z * sR : nullptr;
    #pragma unroll
    for (int fm = 0; fm < 4; ++fm) {
        #pragma unroll
        for (int fn = 0; fn < 4; ++fn) {
            int col = n0 + wc * 64 + fn * 16 + lr;          // D col = lane&15
            int rowb = m0 + wr * 64 + fm * 16 + lk * 4;     // D row = 4*(lane>>4)+j
            #pragma unroll
            for (int j = 0; j < 4; ++j) {
                int row = rowb + j;
                float v = acc[fm][fn][j] * alpha;
                if (BIAS_MODE == 1) v += bias[col];
                if (BIAS_MODE == 2) v += bias[row];
                if (RESID) v += rp[(size_t)row * ldc + col];
                if (OUT_F32) Cf[(size_t)row * ldc + col] = v;
                else         C8[(size_t)row * ldc + col] = f2f8(v);
            }
        }
    }
}

// Fused attention, fp8, kv-tile 64, 8 waves (512 thr), grid 256.
// Software-pipelined: per iteration t the single barrier interval contains
//   [rescale + PV(t) from Ps[t&1],Vs[t&1]]  then  [QK(t+1) from Ks[(t+1)&1]]
//   then softmax(t+1) -> Ps[(t+1)&1].
// PV(t) is independent of softmax(t+1): 128 back-to-back MFMAs per wave per
// interval; other waves' MFMAs cover any wave's softmax VALU (wave slippage).
// Staging at iteration top: K(t+2)->Ks[t&1], V(t+1)->Vs[(t+1)&1] (both target
// buffers whose readers drained before the previous barrier); vmcnt(0) at
// iteration end lands them (~1300cy window > 900cy HBM).
__global__ __launch_bounds__(512, 2)
void flash_attn(const unsigned char* __restrict__ Q,
                const unsigned char* __restrict__ Kg,
                const unsigned char* __restrict__ Vg,
                unsigned char* __restrict__ H)
{
    __shared__ __align__(16) unsigned char Ks[2][64 * 512];  // 64 KB
    __shared__ __align__(16) unsigned char Vs[2][512 * 64];  // 64 KB
    __shared__ __align__(16) unsigned char Ps[2][128 * 72];  // 18 KB
    __shared__ __align__(16) float Ls[2][128];
    __shared__ int flags[2];                                 // rescale epoch

    const int p = blockIdx.x;                // XCD-affinity decode
    const int b  = ((p >> 6) << 3) + (p & 7);
    const int qt = (p >> 3) & 7;

    const int tid = threadIdx.x;
    const int w = tid >> 6, lane = tid & 63;
    const int lr = lane & 15, lk = lane >> 4;
    const int q0 = qt * 128 + w * 16;

    // Q frags (B-operand): lane holds Q[q0+lr][st*32 + lk*8 + e], fp8
    i64v qf[16];
    const unsigned char* qp = Q + ((size_t)b * NSP + q0 + lr) * 1024 + lk * 8;
    #pragma unroll
    for (int st = 0; st < 16; ++st) qf[st] = *(const i64v*)(qp + st * 32);

    f32x4 o[8][4] = {};          // [qf2][cf]: q = qf2*16+4lk+j, c = w*64+cf*16+lr
    float m = -3.0e38f, l = 0.f;

    const unsigned char* Kb = Kg + (size_t)b * NSP * 1024;   // rows 1024B (Q|K)
    const unsigned char* Vb = Vg + (size_t)b * CD * 1024;

    auto stageK = [&](int t, int buf) {      // 64 rows x 512B; 8 rows/wave
        int kv0 = t * 64;
        #pragma unroll
        for (int i = 0; i < 4; ++i) {
            int rb = i * 16 + w * 2;
            int row = rb + (lane >> 5);
            int src = (lane & 31) ^ (row & 7);
            gl_lds16(Kb + (size_t)(kv0 + row) * 1024 + src * 16, &Ks[buf][rb * 512]);
        }
    };
    auto stageV = [&](int t, int buf) {      // 512 rows x 64B; 64 rows/wave
        int kv0 = t * 64;
        #pragma unroll
        for (int i = 0; i < 4; ++i) {
            int cb = i * 128 + w * 16;
            int c = cb + (lane >> 2);
            int src = (lane & 3) ^ ((c >> 1) & 3);
            gl_lds16(Vb + (size_t)c * 1024 + kv0 + src * 16, &Vs[buf][cb * 64]);
        }
    };

    // QK^T + softmax for tile tau -> Ps[tau&1]. S^T[kv][q=lr], kv=kvf*16+4lk+j.
    auto qksm = [&](int tau) {
        const int pb = tau & 1;
        const unsigned char* Kc = &Ks[pb][0];
        f32x4 s[4] = {};
        __builtin_amdgcn_s_setprio(1);
        #pragma unroll
        for (int st = 0; st < 16; ++st) {
            int c16 = st * 2 + (lk >> 1);
            int half = (lk & 1) * 8;
            #pragma unroll
            for (int kvf = 0; kvf < 4; ++kvf) {
                int row = kvf * 16 + lr;
                i64v kf = *(const i64v*)&Kc[row * 512 + ((c16 ^ (row & 7)) << 4) + half];
                s[kvf] = __builtin_amdgcn_mfma_f32_16x16x32_fp8_fp8(kf, qf[st], s[kvf], 0, 0, 0);
            }
        }
        __builtin_amdgcn_s_setprio(0);
        #pragma unroll
        for (int kvf = 0; kvf < 4; ++kvf)
            #pragma unroll
            for (int j = 0; j < 4; ++j) s[kvf][j] *= SCALE_EXP2;

        float pm = fmaxf(fmaxf(fmaxf(s[0][0], s[0][1]), fmaxf(s[0][2], s[0][3])),
                         fmaxf(fmaxf(s[1][0], s[1][1]), fmaxf(s[1][2], s[1][3])));
        pm = fmaxf(pm, fmaxf(fmaxf(fmaxf(s[2][0], s[2][1]), fmaxf(s[2][2], s[2][3])),
                             fmaxf(fmaxf(s[3][0], s[3][1]), fmaxf(s[3][2], s[3][3]))));
        pm = fmaxf(pm, __shfl_xor(pm, 16));
        pm = fmaxf(pm, __shfl_xor(pm, 32));
        bool ev = !__all(pm - m <= 8.0f);       // defer-max: P <= 2^8 < 448
        float mn = fmaxf(m, pm);
        float sc = ev ? exp2f(m - mn) : 1.0f;
        if (ev) { m = mn; l *= sc; }
        if (lk == 0) Ls[pb][w * 16 + lr] = sc;
        if (ev && lane == 0) flags[pb] = tau;   // epoch flag

        float rs = 0.f;
        #pragma unroll
        for (int kvf = 0; kvf < 4; ++kvf)
            #pragma unroll
            for (int j = 0; j < 4; ++j) {
                s[kvf][j] = exp2f(s[kvf][j] - m);
                rs += s[kvf][j];
            }
        rs += __shfl_xor(rs, 16);
        rs += __shfl_xor(rs, 32);
        l += rs;

        #pragma unroll
        for (int kvf = 0; kvf < 4; ++kvf) {
            unsigned int pk = f4_to_f8x4(s[kvf][0], s[kvf][1], s[kvf][2], s[kvf][3]);
            *(unsigned int*)&Ps[pb][(w * 16 + lr) * 72 + kvf * 16 + lk * 4] = pk;
        }
    };

    if (tid == 0) { flags[0] = -1; flags[1] = -1; }
    stageK(0, 0); stageV(0, 0);
    asm volatile("s_waitcnt vmcnt(0) lgkmcnt(0)" ::: "memory");
    __builtin_amdgcn_s_barrier();
    stageK(1, 1);
    qksm(0);                                    // P(0) -> Ps[0]
    asm volatile("s_waitcnt vmcnt(0) lgkmcnt(0)" ::: "memory");
    __builtin_amdgcn_s_barrier();               // P(0) visible; K(1) landed

    for (int t = 0; t < 16; ++t) {
        const int cur = t & 1;
        if (t < 14) stageK(t + 2, cur);         // Ks[cur]: readers drained at t-1
        if (t < 15) stageV(t + 1, cur ^ 1);     // Vs[cur^1]: readers drained at t-1

        // ---- rescale + PV(t): wave owns c-slice [w*64,(w+1)*64), all 128 q ----
        if (flags[cur] == t) {
            #pragma unroll
            for (int qf2 = 0; qf2 < 8; ++qf2) {
                f32x4 scv = *(const f32x4*)&Ls[cur][qf2 * 16 + lk * 4];
                #pragma unroll
                for (int cf = 0; cf < 4; ++cf) {
                    o[qf2][cf][0] *= scv[0]; o[qf2][cf][1] *= scv[1];
                    o[qf2][cf][2] *= scv[2]; o[qf2][cf][3] *= scv[3];
                }
            }
        }
        const unsigned char* Vc = &Vs[cur][0];
        __builtin_amdgcn_s_setprio(1);
        #pragma unroll
        for (int ks = 0; ks < 2; ++ks) {
            int c16 = ks * 2 + (lk >> 1);
            int half = (lk & 1) * 8;
            i64v vfr[4];
            #pragma unroll
            for (int cf = 0; cf < 4; ++cf) {
                int c = w * 64 + cf * 16 + lr;
                vfr[cf] = *(const i64v*)&Vc[c * 64 + ((c16 ^ ((c >> 1) & 3)) << 4) + half];
            }
            #pragma unroll
            for (int qf2 = 0; qf2 < 8; ++qf2) {
                i64v pa = *(const i64v*)&Ps[cur][(qf2 * 16 + lr) * 72 + ks * 32 + lk * 8];
                #pragma unroll
                for (int cf = 0; cf < 4; ++cf)
                    o[qf2][cf] = __builtin_amdgcn_mfma_f32_16x16x32_fp8_fp8(
                        pa, vfr[cf], o[qf2][cf], 0, 0, 0);
            }
        }
        __builtin_amdgcn_s_setprio(0);

        // ---- QK(t+1) + softmax(t+1) -> Ps[cur^1] ----
        if (t < 15) qksm(t + 1);

        asm volatile("s_waitcnt vmcnt(0) lgkmcnt(0)" ::: "memory");
        __builtin_amdgcn_s_barrier();
    }

    // epilogue: 1/l per q-row via Ls[0], write H fp8
    if (lk == 0) Ls[0][w * 16 + lr] = 1.0f / l;
    asm volatile("s_waitcnt lgkmcnt(0)" ::: "memory");
    __builtin_amdgcn_s_barrier();
    unsigned char* Hp = H + ((size_t)b * NSP + qt * 128) * CD + w * 64;
    #pragma unroll
    for (int qf2 = 0; qf2 < 8; ++qf2) {
        f32x4 li = *(const f32x4*)&Ls[0][qf2 * 16 + lk * 4];
        #pragma unroll
        for (int cf = 0; cf < 4; ++cf) {
            #pragma unroll
            for (int j = 0; j < 4; ++j)
                Hp[(size_t)(qf2 * 16 + lk * 4 + j) * CD + cf * 16 + lr] =
                    f2f8(o[qf2][cf][j] * li[j]);
        }
    }
}

extern "C" void kernel_launch(void* const* d_in, const int* in_sizes, int n_in,
                              void* d_out, int out_size, void* d_ws, size_t ws_size,
                              hipStream_t stream)
{
    const float* x  = (const float*)d_in[0];
    const float* Wq = (const float*)d_in[1];
    const float* bq = (const float*)d_in[2];
    const float* Wk = (const float*)d_in[3];
    const float* bk = (const float*)d_in[4];
    const float* Wv = (const float*)d_in[5];
    const float* bv = (const float*)d_in[6];
    const float* Wo = (const float*)d_in[7];
    const float* bo = (const float*)d_in[8];
    float* out = (float*)d_out;

    unsigned char* w = (unsigned char*)d_ws;   // byte layout, 16B-aligned
    unsigned char* W8  = w;                     // Wq|Wk|Wv|Wo(x2^22) fp8, 1 MB
    float*         bqk = (float*)(w + 1048576); // 4 KB
    unsigned char* Xt8 = w + 1052672;           // [B][N][C] fp8, 16 MB
    unsigned char* QK8 = w + 17829888;          // [B][N][1024] fp8, 32 MB
    unsigned char* Vc8 = w + 51384320;          // [B][C][N] fp8, 16 MB
    unsigned char* H8  = w + 68161536;          // [B][N][C] fp8, 16 MB

    cvt_all<<<4096, 256, 0, stream>>>(Wq, Wk, Wv, Wo, bq, bk, W8, bqk);
    transpose_x<<<dim3(32, 16, 32), dim3(32, 8), 0, stream>>>(x, Xt8);

    // QK = Xt * [Wq;Wk]^T + [bq;bk]   [32768 x 1024] fp8
    gemm_bt8<1, false, false><<<dim3(8, 256, 1), 256, 0, stream>>>(
        Xt8, W8, QK8, bqk, nullptr, 512, 512, 512, 1024, 0, 0, 0, 0, 1.0f);

    // V in [C][N] fp8: A=Wv fp8, B=Xt_b, bias per-row(c)
    gemm_bt8<2, false, false><<<dim3(8, 4, 32), 256, 0, stream>>>(
        W8 + 524288, Xt8, Vc8, bv, nullptr, 512, 512, 512, 1024,
        0, 524288, 524288, 0, 1.0f);

    // fused attention -> H8 [B][N][C] fp8
    flash_attn<<<256, 512, 0, stream>>>(QK8, QK8 + 512, Vc8, H8);

    // out = (Wo*2^22) * H_b^T * 2^-22 + bo(row) + x   [C][N] fp32
    gemm_bt8<2, true, true><<<dim3(8, 4, 32), 256, 0, stream>>>(
        W8 + 786432, H8, out, bo, x, 512, 512, 512, 1024,
        0, 524288, 524288, 524288, WO_INV);
}